// Round 1
// baseline (1032.221 us; speedup 1.0000x reference)
//
#include <hip/hip_runtime.h>
#include <math.h>

#define NN 50000
#define NE 800000
#define NB 512
#define FIN 74
#define HD 64
#define BN_EPS 1e-5f

// ---------------- kernels ----------------

// agg[i][c] = b[c]; also zero the 128-float stats block
__global__ void init_agg_kernel(float* __restrict__ agg, const float* __restrict__ b,
                                float* __restrict__ stats, int n) {
    int idx = blockIdx.x * 256 + threadIdx.x;
    if (idx < 128) stats[idx] = 0.f;
    int total = n * HD;
    for (int i = idx; i < total; i += gridDim.x * 256) agg[i] = b[i & 63];
}

// y[N][64] = x[N][K] @ W[K][64]
template <int K>
__global__ void gemm_kernel(const float* __restrict__ x, const float* __restrict__ W,
                            float* __restrict__ y, int n) {
    __shared__ float sW[K * HD];
    for (int i = threadIdx.x; i < K * HD; i += 256) sW[i] = W[i];
    __syncthreads();
    int row = blockIdx.x * 4 + (threadIdx.x >> 6);
    if (row >= n) return;
    int col = threadIdx.x & 63;
    const float* xr = x + (size_t)row * K;
    float acc = 0.f;
#pragma unroll 2
    for (int k = 0; k < K; ++k) acc = fmaf(xr[k], sW[k * HD + col], acc);
    y[(size_t)row * HD + col] = acc;
}

// agg[dst[e]][c] += xw[src[e]][c]  (edge-parallel atomics)
__global__ void scatter_kernel(const float* __restrict__ xw, const int* __restrict__ src,
                               const int* __restrict__ dst, float* __restrict__ agg) {
    int idx = blockIdx.x * 256 + threadIdx.x;
    int e = idx >> 6;
    if (e >= NE) return;
    int c = idx & 63;
    int s = src[e], d = dst[e];
    atomicAdd(&agg[(size_t)d * HD + c], xw[(size_t)s * HD + c]);
}

// h = relu(agg) + relu(x @ rW + rb)   (agg already contains +b)
template <int K>
__global__ void combine_kernel(const float* __restrict__ x, const float* __restrict__ rW,
                               const float* __restrict__ rb, const float* __restrict__ agg,
                               float* __restrict__ h, int n) {
    __shared__ float sW[K * HD];
    for (int i = threadIdx.x; i < K * HD; i += 256) sW[i] = rW[i];
    __syncthreads();
    int row = blockIdx.x * 4 + (threadIdx.x >> 6);
    if (row >= n) return;
    int col = threadIdx.x & 63;
    const float* xr = x + (size_t)row * K;
    float acc = rb[col];
#pragma unroll 2
    for (int k = 0; k < K; ++k) acc = fmaf(xr[k], sW[k * HD + col], acc);
    float a = agg[(size_t)row * HD + col];
    h[(size_t)row * HD + col] = fmaxf(a, 0.f) + fmaxf(acc, 0.f);
}

// per-column sum & sumsq over rows (two-stage: block partials -> atomics)
__global__ void colstats_kernel(const float* __restrict__ h, float* __restrict__ stats, int n) {
    int c = threadIdx.x & 63;
    int rl = threadIdx.x >> 6;  // 0..3
    float s = 0.f, s2 = 0.f;
    for (int row = blockIdx.x * 4 + rl; row < n; row += gridDim.x * 4) {
        float v = h[(size_t)row * HD + c];
        s += v;
        s2 += v * v;
    }
    __shared__ float ls[256], ls2[256];
    ls[threadIdx.x] = s;
    ls2[threadIdx.x] = s2;
    __syncthreads();
    if (rl == 0) {
        s = ls[c] + ls[64 + c] + ls[128 + c] + ls[192 + c];
        s2 = ls2[c] + ls2[64 + c] + ls2[128 + c] + ls2[192 + c];
        atomicAdd(&stats[c], s);
        atomicAdd(&stats[64 + c], s2);
    }
}

// scale/shift from stats
__global__ void bnfinal_kernel(const float* __restrict__ stats, const float* __restrict__ g,
                               const float* __restrict__ be, float* __restrict__ ss, int n) {
    int c = threadIdx.x;
    float mean = stats[c] / (float)n;
    float var = stats[64 + c] / (float)n - mean * mean;
    float scale = g[c] * rsqrtf(var + BN_EPS);
    ss[c] = scale;
    ss[64 + c] = be[c] - mean * scale;
}

__global__ void bnapply_kernel(float* __restrict__ h, const float* __restrict__ ss, int n) {
    int idx = blockIdx.x * 256 + threadIdx.x;
    int total = n * HD;
    for (int i = idx; i < total; i += gridDim.x * 256) {
        int c = i & 63;
        h[i] = fmaf(h[i], ss[c], ss[64 + c]);
    }
}

__global__ void readout_init_kernel(float* __restrict__ hsum, unsigned int* __restrict__ hmax) {
    int idx = blockIdx.x * 256 + threadIdx.x;
    if (idx < NB * HD) {
        hsum[idx] = 0.f;
        hmax[idx] = 0x007FFFFFu;  // encoded(-inf)
    }
}

// one wave (64 lanes) per node: lanes = columns
__global__ void readout_kernel(const float* __restrict__ h, const int* __restrict__ gid,
                               const float* __restrict__ awW, const float* __restrict__ awb,
                               float* __restrict__ hsum, unsigned int* __restrict__ hmax, int n) {
    int node = blockIdx.x * 4 + (threadIdx.x >> 6);
    if (node >= n) return;
    int c = threadIdx.x & 63;
    float v = h[(size_t)node * HD + c];
    float p = v * awW[c];
    for (int off = 32; off; off >>= 1) p += __shfl_xor(p, off, 64);
    float w = 1.f / (1.f + expf(-(p + awb[0])));
    int g = gid[node];
    atomicAdd(&hsum[g * HD + c], v * w);
    unsigned int bits = __float_as_uint(v);
    unsigned int enc = (bits & 0x80000000u) ? ~bits : (bits | 0x80000000u);
    atomicMax(&hmax[g * HD + c], enc);
}

// out[B][64] = [hsum | hmax] @ outW[128][64] + outb
__global__ void final_kernel(const float* __restrict__ hsum, const unsigned int* __restrict__ hmax,
                             const float* __restrict__ outW, const float* __restrict__ outb,
                             float* __restrict__ out) {
    __shared__ float sW[128 * 64];
    for (int i = threadIdx.x; i < 128 * 64; i += 256) sW[i] = outW[i];
    __syncthreads();
    int idx = blockIdx.x * 256 + threadIdx.x;
    if (idx >= NB * HD) return;
    int b = idx >> 6, o = idx & 63;
    float acc = outb[o];
#pragma unroll 4
    for (int k = 0; k < 64; ++k) acc = fmaf(hsum[b * 64 + k], sW[k * 64 + o], acc);
#pragma unroll 4
    for (int k = 0; k < 64; ++k) {
        unsigned int e = hmax[b * 64 + k];
        float m;
        if (e == 0x007FFFFFu) {
            m = 0.f;  // empty graph: -inf -> 0
        } else {
            m = (e & 0x80000000u) ? __uint_as_float(e ^ 0x80000000u) : __uint_as_float(~e);
        }
        acc = fmaf(m, sW[(64 + k) * 64 + o], acc);
    }
    out[idx] = acc;
}

// ---------------- launch ----------------

extern "C" void kernel_launch(void* const* d_in, const int* in_sizes, int n_in,
                              void* d_out, int out_size, void* d_ws, size_t ws_size,
                              hipStream_t stream) {
    const float* feats = (const float*)d_in[0];
    const int* src = (const int*)d_in[1];
    const int* dst = (const int*)d_in[2];
    const int* gid = (const int*)d_in[3];
    // per-layer params: W, b, rW, rb, g, be at 4 + 6*l
    const float* W[3];
    const float* b[3];
    const float* rW[3];
    const float* rb[3];
    const float* g[3];
    const float* be[3];
    for (int l = 0; l < 3; ++l) {
        W[l] = (const float*)d_in[4 + 6 * l + 0];
        b[l] = (const float*)d_in[4 + 6 * l + 1];
        rW[l] = (const float*)d_in[4 + 6 * l + 2];
        rb[l] = (const float*)d_in[4 + 6 * l + 3];
        g[l] = (const float*)d_in[4 + 6 * l + 4];
        be[l] = (const float*)d_in[4 + 6 * l + 5];
    }
    const float* awW = (const float*)d_in[22];
    const float* awb = (const float*)d_in[23];
    const float* outW = (const float*)d_in[24];
    const float* outb = (const float*)d_in[25];
    float* out = (float*)d_out;

    // workspace layout
    float* P0 = (float*)d_ws;            // N*64  (xw scratch)
    float* P1 = P0 + (size_t)NN * HD;    // N*64
    float* P2 = P1 + (size_t)NN * HD;    // N*64
    float* stats = P2 + (size_t)NN * HD; // 128
    float* ss = stats + 128;             // 128
    float* hsum = ss + 128;              // B*64
    unsigned int* hmax = (unsigned int*)(hsum + (size_t)NB * HD);  // B*64

    const int ROWBLK = (NN + 3) / 4;            // 12500
    const int SCATBLK = (NE * 64 + 255) / 256;  // 200000

    // layer 0: x = feats (K=74), xw=P0, agg/h = P1
    init_agg_kernel<<<2048, 256, 0, stream>>>(P1, b[0], stats, NN);
    gemm_kernel<FIN><<<ROWBLK, 256, 0, stream>>>(feats, W[0], P0, NN);
    scatter_kernel<<<SCATBLK, 256, 0, stream>>>(P0, src, dst, P1);
    combine_kernel<FIN><<<ROWBLK, 256, 0, stream>>>(feats, rW[0], rb[0], P1, P1, NN);
    colstats_kernel<<<512, 256, 0, stream>>>(P1, stats, NN);
    bnfinal_kernel<<<1, 64, 0, stream>>>(stats, g[0], be[0], ss, NN);
    bnapply_kernel<<<2048, 256, 0, stream>>>(P1, ss, NN);

    // layer 1: x = P1 (K=64), xw=P0, agg/h = P2
    init_agg_kernel<<<2048, 256, 0, stream>>>(P2, b[1], stats, NN);
    gemm_kernel<HD><<<ROWBLK, 256, 0, stream>>>(P1, W[1], P0, NN);
    scatter_kernel<<<SCATBLK, 256, 0, stream>>>(P0, src, dst, P2);
    combine_kernel<HD><<<ROWBLK, 256, 0, stream>>>(P1, rW[1], rb[1], P2, P2, NN);
    colstats_kernel<<<512, 256, 0, stream>>>(P2, stats, NN);
    bnfinal_kernel<<<1, 64, 0, stream>>>(stats, g[1], be[1], ss, NN);
    bnapply_kernel<<<2048, 256, 0, stream>>>(P2, ss, NN);

    // layer 2: x = P2 (K=64), xw=P0, agg/h = P1
    init_agg_kernel<<<2048, 256, 0, stream>>>(P1, b[2], stats, NN);
    gemm_kernel<HD><<<ROWBLK, 256, 0, stream>>>(P2, W[2], P0, NN);
    scatter_kernel<<<SCATBLK, 256, 0, stream>>>(P0, src, dst, P1);
    combine_kernel<HD><<<ROWBLK, 256, 0, stream>>>(P2, rW[2], rb[2], P1, P1, NN);
    colstats_kernel<<<512, 256, 0, stream>>>(P1, stats, NN);
    bnfinal_kernel<<<1, 64, 0, stream>>>(stats, g[2], be[2], ss, NN);
    bnapply_kernel<<<2048, 256, 0, stream>>>(P1, ss, NN);

    // readout
    readout_init_kernel<<<(NB * HD + 255) / 256, 256, 0, stream>>>(hsum, hmax);
    readout_kernel<<<ROWBLK, 256, 0, stream>>>(P1, gid, awW, awb, hsum, hmax, NN);
    final_kernel<<<(NB * HD + 255) / 256, 256, 0, stream>>>(hsum, hmax, outW, outb, out);
}

// Round 2
// 697.887 us; speedup vs baseline: 1.4791x; 1.4791x over previous
//
#include <hip/hip_runtime.h>
#include <math.h>

#define NN 50000
#define NE 800000
#define NB 512
#define FIN 74
#define HD 64
#define BN_EPS 1e-5f

#define SCHUNK 512
#define NCHUNK ((NN + SCHUNK - 1) / SCHUNK)  // 98

// ---------------- CSR build ----------------

__global__ void csr_zero_kernel(int* __restrict__ cnt, int* __restrict__ cnt2,
                                float* __restrict__ stats012) {
    int i = blockIdx.x * 256 + threadIdx.x;
    if (i < NN) { cnt[i] = 0; cnt2[i] = 0; }
    if (i < 384) stats012[i] = 0.f;  // stats0|stats1|stats2
}

__global__ void csr_hist_kernel(const int* __restrict__ dst, int* __restrict__ cnt) {
    int e = blockIdx.x * 256 + threadIdx.x;
    if (e < NE) atomicAdd(&cnt[dst[e]], 1);
}

__global__ void scanA_kernel(const int* __restrict__ cnt, int* __restrict__ bsum) {
    __shared__ int l[SCHUNK];
    int i = blockIdx.x * SCHUNK + threadIdx.x;
    int v = (i < NN) ? cnt[i] : 0;
    l[threadIdx.x] = v;
    __syncthreads();
    for (int off = SCHUNK / 2; off; off >>= 1) {
        if (threadIdx.x < off) l[threadIdx.x] += l[threadIdx.x + off];
        __syncthreads();
    }
    if (threadIdx.x == 0) bsum[blockIdx.x] = l[0];
}

__global__ void scanB_kernel(int* __restrict__ bsum) {
    if (threadIdx.x == 0) {
        int acc = 0;
        for (int i = 0; i < NCHUNK; ++i) { int v = bsum[i]; bsum[i] = acc; acc += v; }
    }
}

__global__ void scanC_kernel(const int* __restrict__ cnt, const int* __restrict__ bsum,
                             int* __restrict__ row_ptr) {
    __shared__ int l[SCHUNK];
    int i = blockIdx.x * SCHUNK + threadIdx.x;
    int v = (i < NN) ? cnt[i] : 0;
    l[threadIdx.x] = v;
    __syncthreads();
    // inclusive Hillis-Steele scan
    for (int off = 1; off < SCHUNK; off <<= 1) {
        int t = (threadIdx.x >= off) ? l[threadIdx.x - off] : 0;
        __syncthreads();
        l[threadIdx.x] += t;
        __syncthreads();
    }
    int excl = l[threadIdx.x] - v + bsum[blockIdx.x];
    if (i < NN) row_ptr[i] = excl;
    if (i == NN - 1) row_ptr[NN] = excl + v;
}

__global__ void csr_fill_kernel(const int* __restrict__ src, const int* __restrict__ dst,
                                const int* __restrict__ row_ptr, int* __restrict__ cnt2,
                                int* __restrict__ eidx) {
    int e = blockIdx.x * 256 + threadIdx.x;
    if (e < NE) {
        int d = dst[e];
        int p = row_ptr[d] + atomicAdd(&cnt2[d], 1);
        eidx[p] = src[e];
    }
}

// ---------------- dense pieces ----------------

// y[N][64] = x[N][K] @ W[K][64]
template <int K>
__global__ void gemm_kernel(const float* __restrict__ x, const float* __restrict__ W,
                            float* __restrict__ y, int n) {
    __shared__ float sW[K * HD];
    for (int i = threadIdx.x; i < K * HD; i += 256) sW[i] = W[i];
    __syncthreads();
    int row = blockIdx.x * 4 + (threadIdx.x >> 6);
    if (row >= n) return;
    int col = threadIdx.x & 63;
    const float* xr = x + (size_t)row * K;
    float acc = 0.f;
#pragma unroll 4
    for (int k = 0; k < K; ++k) acc = fmaf(xr[k], sW[k * HD + col], acc);
    y[(size_t)row * HD + col] = acc;
}

// BN fold for layer l>=1: from prev-layer stats + BN params, produce
// Wp = diag(scale) W, rWp = diag(scale) rW, shiftW = shift @ W, rbp = rb + shift @ rW
__global__ void fold_kernel(const float* __restrict__ stats, const float* __restrict__ g,
                            const float* __restrict__ be, const float* __restrict__ W,
                            const float* __restrict__ rW, const float* __restrict__ rb,
                            float* __restrict__ Wp, float* __restrict__ rWp,
                            float* __restrict__ shiftW, float* __restrict__ rbp) {
    __shared__ float sc[64], sh[64];
    int t = threadIdx.x;
    if (t < 64) {
        float mean = stats[t] / (float)NN;
        float var = stats[64 + t] / (float)NN - mean * mean;
        float scale = g[t] * rsqrtf(var + BN_EPS);
        sc[t] = scale;
        sh[t] = be[t] - mean * scale;
    }
    __syncthreads();
    for (int i = t; i < 64 * 64; i += 256) {
        int k = i >> 6;
        Wp[i] = sc[k] * W[i];
        rWp[i] = sc[k] * rW[i];
    }
    if (t < 64) {
        float sw = 0.f, srw = 0.f;
        for (int k = 0; k < 64; ++k) {
            sw = fmaf(sh[k], W[k * 64 + t], sw);
            srw = fmaf(sh[k], rW[k * 64 + t], srw);
        }
        shiftW[t] = sw;
        rbp[t] = rb[t] + srw;
    }
}

// fused: h = relu( gather-sum(xw) + deg*shiftW + b ) + relu( x @ rWp + rbp ); stats += (h, h^2)
template <int K>
__global__ void fused_layer_kernel(const float* __restrict__ x, const float* __restrict__ xw,
                                   const float* __restrict__ rWp, const float* __restrict__ rbp,
                                   const float* __restrict__ b, const float* __restrict__ shiftW,
                                   const int* __restrict__ row_ptr, const int* __restrict__ eidx,
                                   float* __restrict__ hout, float* __restrict__ stats, int n) {
    __shared__ float sW[K * HD];
    __shared__ float sb[64], srb[64], ssw[64];
    __shared__ float ls[256], ls2[256];
    for (int i = threadIdx.x; i < K * HD; i += 256) sW[i] = rWp[i];
    if (threadIdx.x < 64) {
        sb[threadIdx.x] = b[threadIdx.x];
        srb[threadIdx.x] = rbp[threadIdx.x];
        ssw[threadIdx.x] = shiftW ? shiftW[threadIdx.x] : 0.f;
    }
    __syncthreads();
    int wl = threadIdx.x >> 6, c = threadIdx.x & 63;
    float s = 0.f, s2 = 0.f;
    for (int row = blockIdx.x * 4 + wl; row < n; row += gridDim.x * 4) {
        const float* xr = x + (size_t)row * K;
        float res = srb[c];
#pragma unroll 8
        for (int k = 0; k < K; ++k) res = fmaf(xr[k], sW[k * HD + c], res);
        int beg = row_ptr[row], end = row_ptr[row + 1];
        float agg = fmaf((float)(end - beg), ssw[c], sb[c]);
        for (int e0 = beg; e0 < end; e0 += 64) {
            int m = end - e0;
            if (m > 64) m = 64;
            int my = (c < m) ? eidx[e0 + c] : 0;
            for (int j = 0; j < m; ++j) {
                int sidx = __shfl(my, j, 64);
                agg += xw[(size_t)sidx * HD + c];
            }
        }
        float hv = fmaxf(agg, 0.f) + fmaxf(res, 0.f);
        hout[(size_t)row * HD + c] = hv;
        s += hv;
        s2 += hv * hv;
    }
    ls[threadIdx.x] = s;
    ls2[threadIdx.x] = s2;
    __syncthreads();
    if (wl == 0) {
        float a = ls[c] + ls[64 + c] + ls[128 + c] + ls[192 + c];
        float a2 = ls2[c] + ls2[64 + c] + ls2[128 + c] + ls2[192 + c];
        atomicAdd(&stats[c], a);
        atomicAdd(&stats[64 + c], a2);
    }
}

// ---------------- readout ----------------

__global__ void readout_init_kernel(float* __restrict__ hsum, unsigned int* __restrict__ hmax,
                                    const float* __restrict__ stats, const float* __restrict__ g,
                                    const float* __restrict__ be, float* __restrict__ ss) {
    int idx = blockIdx.x * 256 + threadIdx.x;
    if (idx < NB * HD) {
        hsum[idx] = 0.f;
        hmax[idx] = 0x007FFFFFu;  // encoded(-inf)
    }
    if (blockIdx.x == 0 && threadIdx.x < 64) {
        int c = threadIdx.x;
        float mean = stats[c] / (float)NN;
        float var = stats[64 + c] / (float)NN - mean * mean;
        float scale = g[c] * rsqrtf(var + BN_EPS);
        ss[c] = scale;
        ss[64 + c] = be[c] - mean * scale;
    }
}

// one wave per node; BN of last layer applied on the fly via ss
__global__ void readout_kernel(const float* __restrict__ h, const int* __restrict__ gid,
                               const float* __restrict__ ss, const float* __restrict__ awW,
                               const float* __restrict__ awb, float* __restrict__ hsum,
                               unsigned int* __restrict__ hmax, int n) {
    int node = blockIdx.x * 4 + (threadIdx.x >> 6);
    if (node >= n) return;
    int c = threadIdx.x & 63;
    float v = fmaf(h[(size_t)node * HD + c], ss[c], ss[64 + c]);
    float p = v * awW[c];
    for (int off = 32; off; off >>= 1) p += __shfl_xor(p, off, 64);
    float w = 1.f / (1.f + expf(-(p + awb[0])));
    int g = gid[node];
    atomicAdd(&hsum[g * HD + c], v * w);
    unsigned int bits = __float_as_uint(v);
    unsigned int enc = (bits & 0x80000000u) ? ~bits : (bits | 0x80000000u);
    atomicMax(&hmax[g * HD + c], enc);
}

__global__ void final_kernel(const float* __restrict__ hsum, const unsigned int* __restrict__ hmax,
                             const float* __restrict__ outW, const float* __restrict__ outb,
                             float* __restrict__ out) {
    __shared__ float sW[128 * 64];
    for (int i = threadIdx.x; i < 128 * 64; i += 256) sW[i] = outW[i];
    __syncthreads();
    int idx = blockIdx.x * 256 + threadIdx.x;
    if (idx >= NB * HD) return;
    int bi = idx >> 6, o = idx & 63;
    float acc = outb[o];
#pragma unroll 4
    for (int k = 0; k < 64; ++k) acc = fmaf(hsum[bi * 64 + k], sW[k * 64 + o], acc);
#pragma unroll 4
    for (int k = 0; k < 64; ++k) {
        unsigned int e = hmax[bi * 64 + k];
        float m;
        if (e == 0x007FFFFFu) {
            m = 0.f;  // empty graph
        } else {
            m = (e & 0x80000000u) ? __uint_as_float(e ^ 0x80000000u) : __uint_as_float(~e);
        }
        acc = fmaf(m, sW[(64 + k) * 64 + o], acc);
    }
    out[idx] = acc;
}

// ---------------- launch ----------------

extern "C" void kernel_launch(void* const* d_in, const int* in_sizes, int n_in,
                              void* d_out, int out_size, void* d_ws, size_t ws_size,
                              hipStream_t stream) {
    const float* feats = (const float*)d_in[0];
    const int* src = (const int*)d_in[1];
    const int* dst = (const int*)d_in[2];
    const int* gid = (const int*)d_in[3];
    const float* W[3];
    const float* b[3];
    const float* rW[3];
    const float* rb[3];
    const float* g[3];
    const float* be[3];
    for (int l = 0; l < 3; ++l) {
        W[l] = (const float*)d_in[4 + 6 * l + 0];
        b[l] = (const float*)d_in[4 + 6 * l + 1];
        rW[l] = (const float*)d_in[4 + 6 * l + 2];
        rb[l] = (const float*)d_in[4 + 6 * l + 3];
        g[l] = (const float*)d_in[4 + 6 * l + 4];
        be[l] = (const float*)d_in[4 + 6 * l + 5];
    }
    const float* awW = (const float*)d_in[22];
    const float* awb = (const float*)d_in[23];
    const float* outW = (const float*)d_in[24];
    const float* outb = (const float*)d_in[25];
    float* out = (float*)d_out;

    // workspace layout (floats)
    float* P0 = (float*)d_ws;              // N*64 xw
    float* P1 = P0 + (size_t)NN * HD;      // N*64
    float* P2 = P1 + (size_t)NN * HD;      // N*64
    float* stats = P2 + (size_t)NN * HD;   // 3*128 (stats0|stats1|stats2)
    float* ss2 = stats + 384;              // 128
    float* Wp = ss2 + 128;                 // 4096
    float* rWp = Wp + 4096;                // 4096
    float* shW = rWp + 4096;               // 64
    float* rbp = shW + 64;                 // 64
    float* hsum = rbp + 64;                // B*64
    unsigned int* hmax = (unsigned int*)(hsum + (size_t)NB * HD);  // B*64
    int* cnt = (int*)(hmax + (size_t)NB * HD);                     // N
    int* cnt2 = cnt + NN;                                          // N
    int* row_ptr = cnt2 + NN;                                      // N+1
    int* bsum = row_ptr + NN + 1;                                  // NCHUNK
    int* eidx = bsum + NCHUNK;                                     // E

    float* stats0 = stats;
    float* stats1 = stats + 128;
    float* stats2 = stats + 256;

    const int ROWBLK = (NN + 3) / 4;          // 12500
    const int EBLK = (NE + 255) / 256;        // 3125
    const int FUSEBLK = 1024;

    // ---- CSR build ----
    csr_zero_kernel<<<(NN + 255) / 256, 256, 0, stream>>>(cnt, cnt2, stats);
    csr_hist_kernel<<<EBLK, 256, 0, stream>>>(dst, cnt);
    scanA_kernel<<<NCHUNK, SCHUNK, 0, stream>>>(cnt, bsum);
    scanB_kernel<<<1, 64, 0, stream>>>(bsum);
    scanC_kernel<<<NCHUNK, SCHUNK, 0, stream>>>(cnt, bsum, row_ptr);
    csr_fill_kernel<<<EBLK, 256, 0, stream>>>(src, dst, row_ptr, cnt2, eidx);

    // ---- layer 0 (input feats, no BN fold) ----
    gemm_kernel<FIN><<<ROWBLK, 256, 0, stream>>>(feats, W[0], P0, NN);
    fused_layer_kernel<FIN><<<FUSEBLK, 256, 0, stream>>>(feats, P0, rW[0], rb[0], b[0],
                                                         (const float*)nullptr, row_ptr, eidx,
                                                         P1, stats0, NN);

    // ---- layer 1 (fold BN0) ----
    fold_kernel<<<1, 256, 0, stream>>>(stats0, g[0], be[0], W[1], rW[1], rb[1], Wp, rWp, shW, rbp);
    gemm_kernel<HD><<<ROWBLK, 256, 0, stream>>>(P1, Wp, P0, NN);
    fused_layer_kernel<HD><<<FUSEBLK, 256, 0, stream>>>(P1, P0, rWp, rbp, b[1], shW, row_ptr, eidx,
                                                        P2, stats1, NN);

    // ---- layer 2 (fold BN1) ----
    fold_kernel<<<1, 256, 0, stream>>>(stats1, g[1], be[1], W[2], rW[2], rb[2], Wp, rWp, shW, rbp);
    gemm_kernel<HD><<<ROWBLK, 256, 0, stream>>>(P2, Wp, P0, NN);
    fused_layer_kernel<HD><<<FUSEBLK, 256, 0, stream>>>(P2, P0, rWp, rbp, b[2], shW, row_ptr, eidx,
                                                        P1, stats2, NN);

    // ---- readout (BN2 applied on the fly) ----
    readout_init_kernel<<<(NB * HD + 255) / 256, 256, 0, stream>>>(hsum, hmax, stats2, g[2], be[2], ss2);
    readout_kernel<<<ROWBLK, 256, 0, stream>>>(P1, gid, ss2, awW, awb, hsum, hmax, NN);
    final_kernel<<<(NB * HD + 255) / 256, 256, 0, stream>>>(hsum, hmax, outW, outb, out);
}

// Round 3
// 687.146 us; speedup vs baseline: 1.5022x; 1.0156x over previous
//
#include <hip/hip_runtime.h>
#include <hip/hip_bf16.h>
#include <math.h>

#define NN 50000
#define NE 800000
#define NB 512
#define FIN 74
#define HD 64
#define BN_EPS 1e-5f

#define SCHUNK 512
#define NCHUNK ((NN + SCHUNK - 1) / SCHUNK)  // 98

// ---------------- CSR build ----------------

__global__ void csr_zero_kernel(int* __restrict__ cnt, int* __restrict__ cnt2,
                                float* __restrict__ stats012) {
    int i = blockIdx.x * 256 + threadIdx.x;
    if (i < NN) { cnt[i] = 0; cnt2[i] = 0; }
    if (i < 384) stats012[i] = 0.f;  // stats0|stats1|stats2
}

__global__ void csr_hist_kernel(const int* __restrict__ dst, int* __restrict__ cnt) {
    int e = blockIdx.x * 256 + threadIdx.x;
    if (e < NE) atomicAdd(&cnt[dst[e]], 1);
}

__global__ void scanA_kernel(const int* __restrict__ cnt, int* __restrict__ bsum) {
    __shared__ int l[SCHUNK];
    int i = blockIdx.x * SCHUNK + threadIdx.x;
    int v = (i < NN) ? cnt[i] : 0;
    l[threadIdx.x] = v;
    __syncthreads();
    for (int off = SCHUNK / 2; off; off >>= 1) {
        if (threadIdx.x < off) l[threadIdx.x] += l[threadIdx.x + off];
        __syncthreads();
    }
    if (threadIdx.x == 0) bsum[blockIdx.x] = l[0];
}

__global__ void scanB_kernel(int* __restrict__ bsum) {
    if (threadIdx.x == 0) {
        int acc = 0;
        for (int i = 0; i < NCHUNK; ++i) { int v = bsum[i]; bsum[i] = acc; acc += v; }
    }
}

__global__ void scanC_kernel(const int* __restrict__ cnt, const int* __restrict__ bsum,
                             int* __restrict__ row_ptr) {
    __shared__ int l[SCHUNK];
    int i = blockIdx.x * SCHUNK + threadIdx.x;
    int v = (i < NN) ? cnt[i] : 0;
    l[threadIdx.x] = v;
    __syncthreads();
    for (int off = 1; off < SCHUNK; off <<= 1) {
        int t = (threadIdx.x >= off) ? l[threadIdx.x - off] : 0;
        __syncthreads();
        l[threadIdx.x] += t;
        __syncthreads();
    }
    int excl = l[threadIdx.x] - v + bsum[blockIdx.x];
    if (i < NN) row_ptr[i] = excl;
    if (i == NN - 1) row_ptr[NN] = excl + v;
}

__global__ void csr_fill_kernel(const int* __restrict__ src, const int* __restrict__ dst,
                                const int* __restrict__ row_ptr, int* __restrict__ cnt2,
                                int* __restrict__ eidx) {
    int e = blockIdx.x * 256 + threadIdx.x;
    if (e < NE) {
        int d = dst[e];
        int p = row_ptr[d] + atomicAdd(&cnt2[d], 1);
        eidx[p] = src[e];
    }
}

// ---------------- dense pieces ----------------

// y[N][64] = x[N][K] @ W[K][64], output bf16
template <int K>
__global__ void gemm_kernel(const float* __restrict__ x, const float* __restrict__ W,
                            __hip_bfloat16* __restrict__ y, int n) {
    __shared__ float sW[K * HD];
    for (int i = threadIdx.x; i < K * HD; i += 256) sW[i] = W[i];
    __syncthreads();
    int row = blockIdx.x * 4 + (threadIdx.x >> 6);
    if (row >= n) return;
    int col = threadIdx.x & 63;
    const float* xr = x + (size_t)row * K;
    float acc = 0.f;
#pragma unroll 4
    for (int k = 0; k < K; ++k) acc = fmaf(xr[k], sW[k * HD + col], acc);
    y[(size_t)row * HD + col] = __float2bfloat16(acc);
}

// BN fold for layer l>=1
__global__ void fold_kernel(const float* __restrict__ stats, const float* __restrict__ g,
                            const float* __restrict__ be, const float* __restrict__ W,
                            const float* __restrict__ rW, const float* __restrict__ rb,
                            float* __restrict__ Wp, float* __restrict__ rWp,
                            float* __restrict__ shiftW, float* __restrict__ rbp) {
    __shared__ float sc[64], sh[64];
    int t = threadIdx.x;
    if (t < 64) {
        float mean = stats[t] / (float)NN;
        float var = stats[64 + t] / (float)NN - mean * mean;
        float scale = g[t] * rsqrtf(var + BN_EPS);
        sc[t] = scale;
        sh[t] = be[t] - mean * scale;
    }
    __syncthreads();
    for (int i = t; i < 64 * 64; i += 256) {
        int k = i >> 6;
        Wp[i] = sc[k] * W[i];
        rWp[i] = sc[k] * rW[i];
    }
    if (t < 64) {
        float sw = 0.f, srw = 0.f;
        for (int k = 0; k < 64; ++k) {
            sw = fmaf(sh[k], W[k * 64 + t], sw);
            srw = fmaf(sh[k], rW[k * 64 + t], srw);
        }
        shiftW[t] = sw;
        rbp[t] = rb[t] + srw;
    }
}

// fused: h = relu( gather-sum(xw_bf16) + deg*shiftW + b ) + relu( x @ rWp + rbp ); stats += (h, h^2)
template <int K>
__global__ void fused_layer_kernel(const float* __restrict__ x,
                                   const __hip_bfloat16* __restrict__ xw,
                                   const float* __restrict__ rWp, const float* __restrict__ rbp,
                                   const float* __restrict__ b, const float* __restrict__ shiftW,
                                   const int* __restrict__ row_ptr, const int* __restrict__ eidx,
                                   float* __restrict__ hout, float* __restrict__ stats, int n) {
    __shared__ float sW[K * HD];
    __shared__ float sb[64], srb[64], ssw[64];
    __shared__ float ls[256], ls2[256];
    for (int i = threadIdx.x; i < K * HD; i += 256) sW[i] = rWp[i];
    if (threadIdx.x < 64) {
        sb[threadIdx.x] = b[threadIdx.x];
        srb[threadIdx.x] = rbp[threadIdx.x];
        ssw[threadIdx.x] = shiftW ? shiftW[threadIdx.x] : 0.f;
    }
    __syncthreads();
    int wl = threadIdx.x >> 6, c = threadIdx.x & 63;
    float s = 0.f, s2 = 0.f;
    for (int row = blockIdx.x * 4 + wl; row < n; row += gridDim.x * 4) {
        const float* xr = x + (size_t)row * K;
        float res = srb[c];
#pragma unroll 8
        for (int k = 0; k < K; ++k) res = fmaf(xr[k], sW[k * HD + c], res);
        int beg = row_ptr[row], end = row_ptr[row + 1];
        float agg = fmaf((float)(end - beg), ssw[c], sb[c]);
        for (int e0 = beg; e0 < end; e0 += 64) {
            int m = end - e0;
            if (m > 64) m = 64;
            int my = (c < m) ? eidx[e0 + c] : 0;
            float a0 = 0.f, a1 = 0.f, a2 = 0.f, a3 = 0.f;
            int j = 0;
            for (; j + 3 < m; j += 4) {
                int s0 = __shfl(my, j, 64);
                int s1 = __shfl(my, j + 1, 64);
                int s2i = __shfl(my, j + 2, 64);
                int s3 = __shfl(my, j + 3, 64);
                a0 += __bfloat162float(xw[(size_t)s0 * HD + c]);
                a1 += __bfloat162float(xw[(size_t)s1 * HD + c]);
                a2 += __bfloat162float(xw[(size_t)s2i * HD + c]);
                a3 += __bfloat162float(xw[(size_t)s3 * HD + c]);
            }
            for (; j < m; ++j) {
                int s0 = __shfl(my, j, 64);
                a0 += __bfloat162float(xw[(size_t)s0 * HD + c]);
            }
            agg += (a0 + a1) + (a2 + a3);
        }
        float hv = fmaxf(agg, 0.f) + fmaxf(res, 0.f);
        hout[(size_t)row * HD + c] = hv;
        s += hv;
        s2 += hv * hv;
    }
    ls[threadIdx.x] = s;
    ls2[threadIdx.x] = s2;
    __syncthreads();
    if (wl == 0) {
        float a = ls[c] + ls[64 + c] + ls[128 + c] + ls[192 + c];
        float a2 = ls2[c] + ls2[64 + c] + ls2[128 + c] + ls2[192 + c];
        atomicAdd(&stats[c], a);
        atomicAdd(&stats[64 + c], a2);
    }
}

// ---------------- readout ----------------

__global__ void readout_init_kernel(float* __restrict__ hsum, unsigned int* __restrict__ hmax,
                                    const float* __restrict__ stats, const float* __restrict__ g,
                                    const float* __restrict__ be, float* __restrict__ ss) {
    int idx = blockIdx.x * 256 + threadIdx.x;
    if (idx < NB * HD) {
        hsum[idx] = 0.f;
        hmax[idx] = 0x007FFFFFu;  // encoded(-inf)
    }
    if (blockIdx.x == 0 && threadIdx.x < 64) {
        int c = threadIdx.x;
        float mean = stats[c] / (float)NN;
        float var = stats[64 + c] / (float)NN - mean * mean;
        float scale = g[c] * rsqrtf(var + BN_EPS);
        ss[c] = scale;
        ss[64 + c] = be[c] - mean * scale;
    }
}

__global__ void readout_kernel(const float* __restrict__ h, const int* __restrict__ gid,
                               const float* __restrict__ ss, const float* __restrict__ awW,
                               const float* __restrict__ awb, float* __restrict__ hsum,
                               unsigned int* __restrict__ hmax, int n) {
    int node = blockIdx.x * 4 + (threadIdx.x >> 6);
    if (node >= n) return;
    int c = threadIdx.x & 63;
    float v = fmaf(h[(size_t)node * HD + c], ss[c], ss[64 + c]);
    float p = v * awW[c];
    for (int off = 32; off; off >>= 1) p += __shfl_xor(p, off, 64);
    float w = 1.f / (1.f + expf(-(p + awb[0])));
    int g = gid[node];
    atomicAdd(&hsum[g * HD + c], v * w);
    unsigned int bits = __float_as_uint(v);
    unsigned int enc = (bits & 0x80000000u) ? ~bits : (bits | 0x80000000u);
    atomicMax(&hmax[g * HD + c], enc);
}

__global__ void final_kernel(const float* __restrict__ hsum, const unsigned int* __restrict__ hmax,
                             const float* __restrict__ outW, const float* __restrict__ outb,
                             float* __restrict__ out) {
    __shared__ float sW[128 * 64];
    for (int i = threadIdx.x; i < 128 * 64; i += 256) sW[i] = outW[i];
    __syncthreads();
    int idx = blockIdx.x * 256 + threadIdx.x;
    if (idx >= NB * HD) return;
    int bi = idx >> 6, o = idx & 63;
    float acc = outb[o];
#pragma unroll 4
    for (int k = 0; k < 64; ++k) acc = fmaf(hsum[bi * 64 + k], sW[k * 64 + o], acc);
#pragma unroll 4
    for (int k = 0; k < 64; ++k) {
        unsigned int e = hmax[bi * 64 + k];
        float m;
        if (e == 0x007FFFFFu) {
            m = 0.f;  // empty graph
        } else {
            m = (e & 0x80000000u) ? __uint_as_float(e ^ 0x80000000u) : __uint_as_float(~e);
        }
        acc = fmaf(m, sW[(64 + k) * 64 + o], acc);
    }
    out[idx] = acc;
}

// ---------------- launch ----------------

extern "C" void kernel_launch(void* const* d_in, const int* in_sizes, int n_in,
                              void* d_out, int out_size, void* d_ws, size_t ws_size,
                              hipStream_t stream) {
    const float* feats = (const float*)d_in[0];
    const int* src = (const int*)d_in[1];
    const int* dst = (const int*)d_in[2];
    const int* gid = (const int*)d_in[3];
    const float* W[3];
    const float* b[3];
    const float* rW[3];
    const float* rb[3];
    const float* g[3];
    const float* be[3];
    for (int l = 0; l < 3; ++l) {
        W[l] = (const float*)d_in[4 + 6 * l + 0];
        b[l] = (const float*)d_in[4 + 6 * l + 1];
        rW[l] = (const float*)d_in[4 + 6 * l + 2];
        rb[l] = (const float*)d_in[4 + 6 * l + 3];
        g[l] = (const float*)d_in[4 + 6 * l + 4];
        be[l] = (const float*)d_in[4 + 6 * l + 5];
    }
    const float* awW = (const float*)d_in[22];
    const float* awb = (const float*)d_in[23];
    const float* outW = (const float*)d_in[24];
    const float* outb = (const float*)d_in[25];
    float* out = (float*)d_out;

    // workspace layout
    __hip_bfloat16* XW = (__hip_bfloat16*)d_ws;            // N*64 bf16
    float* P1 = (float*)(XW + (size_t)NN * HD);            // N*64 f32
    float* P2 = P1 + (size_t)NN * HD;                      // N*64 f32
    float* stats = P2 + (size_t)NN * HD;                   // 3*128
    float* ss2 = stats + 384;                              // 128
    float* Wp = ss2 + 128;                                 // 4096
    float* rWp = Wp + 4096;                                // 4096
    float* shW = rWp + 4096;                               // 64
    float* rbp = shW + 64;                                 // 64
    float* hsum = rbp + 64;                                // B*64
    unsigned int* hmax = (unsigned int*)(hsum + (size_t)NB * HD);  // B*64
    int* cnt = (int*)(hmax + (size_t)NB * HD);             // N
    int* cnt2 = cnt + NN;                                  // N
    int* row_ptr = cnt2 + NN;                              // N+1
    int* bsum = row_ptr + NN + 1;                          // NCHUNK
    int* eidx = bsum + NCHUNK;                             // E

    float* stats0 = stats;
    float* stats1 = stats + 128;
    float* stats2 = stats + 256;

    const int ROWBLK = (NN + 3) / 4;     // 12500
    const int EBLK = (NE + 255) / 256;   // 3125
    const int FUSEBLK = 4096;

    // ---- CSR build ----
    csr_zero_kernel<<<(NN + 255) / 256, 256, 0, stream>>>(cnt, cnt2, stats);
    csr_hist_kernel<<<EBLK, 256, 0, stream>>>(dst, cnt);
    scanA_kernel<<<NCHUNK, SCHUNK, 0, stream>>>(cnt, bsum);
    scanB_kernel<<<1, 64, 0, stream>>>(bsum);
    scanC_kernel<<<NCHUNK, SCHUNK, 0, stream>>>(cnt, bsum, row_ptr);
    csr_fill_kernel<<<EBLK, 256, 0, stream>>>(src, dst, row_ptr, cnt2, eidx);

    // ---- layer 0 ----
    gemm_kernel<FIN><<<ROWBLK, 256, 0, stream>>>(feats, W[0], XW, NN);
    fused_layer_kernel<FIN><<<FUSEBLK, 256, 0, stream>>>(feats, XW, rW[0], rb[0], b[0],
                                                         (const float*)nullptr, row_ptr, eidx,
                                                         P1, stats0, NN);

    // ---- layer 1 (fold BN0) ----
    fold_kernel<<<1, 256, 0, stream>>>(stats0, g[0], be[0], W[1], rW[1], rb[1], Wp, rWp, shW, rbp);
    gemm_kernel<HD><<<ROWBLK, 256, 0, stream>>>(P1, Wp, XW, NN);
    fused_layer_kernel<HD><<<FUSEBLK, 256, 0, stream>>>(P1, XW, rWp, rbp, b[1], shW, row_ptr, eidx,
                                                        P2, stats1, NN);

    // ---- layer 2 (fold BN1) ----
    fold_kernel<<<1, 256, 0, stream>>>(stats1, g[1], be[1], W[2], rW[2], rb[2], Wp, rWp, shW, rbp);
    gemm_kernel<HD><<<ROWBLK, 256, 0, stream>>>(P2, Wp, XW, NN);
    fused_layer_kernel<HD><<<FUSEBLK, 256, 0, stream>>>(P2, XW, rWp, rbp, b[2], shW, row_ptr, eidx,
                                                        P1, stats2, NN);

    // ---- readout (BN2 on the fly) ----
    readout_init_kernel<<<(NB * HD + 255) / 256, 256, 0, stream>>>(hsum, hmax, stats2, g[2], be[2], ss2);
    readout_kernel<<<ROWBLK, 256, 0, stream>>>(P1, gid, ss2, awW, awb, hsum, hmax, NN);
    final_kernel<<<(NB * HD + 255) / 256, 256, 0, stream>>>(hsum, hmax, outW, outb, out);
}

// Round 4
// 614.484 us; speedup vs baseline: 1.6798x; 1.1182x over previous
//
#include <hip/hip_runtime.h>
#include <hip/hip_bf16.h>
#include <math.h>

#define NN 50000
#define NE 800000
#define NB 512
#define FIN 74
#define HD 64
#define BN_EPS 1e-5f

#define SCHUNK 512
#define NCHUNK ((NN + SCHUNK - 1) / SCHUNK)  // 98

// ---------------- CSR build ----------------

__global__ void csr_zero_kernel(int* __restrict__ cnt, int* __restrict__ cnt2,
                                float* __restrict__ stats012) {
    int i = blockIdx.x * 256 + threadIdx.x;
    if (i < NN) { cnt[i] = 0; cnt2[i] = 0; }
    if (i < 384) stats012[i] = 0.f;  // stats0|stats1|stats2
}

__global__ void csr_hist_kernel(const int* __restrict__ dst, int* __restrict__ cnt) {
    int e = blockIdx.x * 256 + threadIdx.x;
    if (e < NE) atomicAdd(&cnt[dst[e]], 1);
}

__global__ void scanA_kernel(const int* __restrict__ cnt, int* __restrict__ bsum) {
    __shared__ int l[SCHUNK];
    int i = blockIdx.x * SCHUNK + threadIdx.x;
    int v = (i < NN) ? cnt[i] : 0;
    l[threadIdx.x] = v;
    __syncthreads();
    for (int off = SCHUNK / 2; off; off >>= 1) {
        if (threadIdx.x < off) l[threadIdx.x] += l[threadIdx.x + off];
        __syncthreads();
    }
    if (threadIdx.x == 0) bsum[blockIdx.x] = l[0];
}

__global__ void scanB_kernel(int* __restrict__ bsum) {
    if (threadIdx.x == 0) {
        int acc = 0;
        for (int i = 0; i < NCHUNK; ++i) { int v = bsum[i]; bsum[i] = acc; acc += v; }
    }
}

__global__ void scanC_kernel(const int* __restrict__ cnt, const int* __restrict__ bsum,
                             int* __restrict__ row_ptr) {
    __shared__ int l[SCHUNK];
    int i = blockIdx.x * SCHUNK + threadIdx.x;
    int v = (i < NN) ? cnt[i] : 0;
    l[threadIdx.x] = v;
    __syncthreads();
    for (int off = 1; off < SCHUNK; off <<= 1) {
        int t = (threadIdx.x >= off) ? l[threadIdx.x - off] : 0;
        __syncthreads();
        l[threadIdx.x] += t;
        __syncthreads();
    }
    int excl = l[threadIdx.x] - v + bsum[blockIdx.x];
    if (i < NN) row_ptr[i] = excl;
    if (i == NN - 1) row_ptr[NN] = excl + v;
}

__global__ void csr_fill_kernel(const int* __restrict__ src, const int* __restrict__ dst,
                                const int* __restrict__ row_ptr, int* __restrict__ cnt2,
                                int* __restrict__ eidx) {
    int e = blockIdx.x * 256 + threadIdx.x;
    if (e < NE) {
        int d = dst[e];
        int p = row_ptr[d] + atomicAdd(&cnt2[d], 1);
        eidx[p] = src[e];
    }
}

// ---------------- dense pieces ----------------

// y[N][64] = x[N][K] @ W[K][64], output bf16; grid-stride to amortize LDS stage
template <int K>
__global__ __launch_bounds__(256) void gemm_kernel(const float* __restrict__ x,
                                                   const float* __restrict__ W,
                                                   __hip_bfloat16* __restrict__ y, int n) {
    __shared__ float sW[K * HD];
    for (int i = threadIdx.x; i < K * HD; i += 256) sW[i] = W[i];
    __syncthreads();
    int wl = threadIdx.x >> 6, col = threadIdx.x & 63;
    for (int row = blockIdx.x * 4 + wl; row < n; row += gridDim.x * 4) {
        const float* xr = x + (size_t)row * K;
        float acc = 0.f;
#pragma unroll 8
        for (int k = 0; k < K; ++k) acc = fmaf(xr[k], sW[k * HD + col], acc);
        y[(size_t)row * HD + col] = __float2bfloat16(acc);
    }
}

// BN fold for layer l>=1
__global__ void fold_kernel(const float* __restrict__ stats, const float* __restrict__ g,
                            const float* __restrict__ be, const float* __restrict__ W,
                            const float* __restrict__ rW, const float* __restrict__ rb,
                            float* __restrict__ Wp, float* __restrict__ rWp,
                            float* __restrict__ shiftW, float* __restrict__ rbp) {
    __shared__ float sc[64], sh[64];
    int t = threadIdx.x;
    if (t < 64) {
        float mean = stats[t] / (float)NN;
        float var = stats[64 + t] / (float)NN - mean * mean;
        float scale = g[t] * rsqrtf(var + BN_EPS);
        sc[t] = scale;
        sh[t] = be[t] - mean * scale;
    }
    __syncthreads();
    for (int i = t; i < 64 * 64; i += 256) {
        int k = i >> 6;
        Wp[i] = sc[k] * W[i];
        rWp[i] = sc[k] * rW[i];
    }
    if (t < 64) {
        float sw = 0.f, srw = 0.f;
        for (int k = 0; k < 64; ++k) {
            sw = fmaf(sh[k], W[k * 64 + t], sw);
            srw = fmaf(sh[k], rW[k * 64 + t], srw);
        }
        shiftW[t] = sw;
        rbp[t] = rb[t] + srw;
    }
}

__device__ __forceinline__ float bf_lo(unsigned int p) { return __uint_as_float(p << 16); }
__device__ __forceinline__ float bf_hi(unsigned int p) { return __uint_as_float(p & 0xffff0000u); }

// fused: h = relu( gather-sum(xw_bf16) + deg*shiftW + b ) + relu( x @ rWp + rbp ); stats += (h, h^2)
// Gather: 2 edges per wave-instruction (lanes 0-31 = edge A as 32 bf16x2 dwords,
// lanes 32-63 = edge B), unroll 4 -> 8 edges (4 independent dword loads) in flight.
template <int K>
__global__ __launch_bounds__(256) void fused_layer_kernel(
    const float* __restrict__ x, const __hip_bfloat16* __restrict__ xw,
    const float* __restrict__ rWp, const float* __restrict__ rbp, const float* __restrict__ b,
    const float* __restrict__ shiftW, const int* __restrict__ row_ptr,
    const int* __restrict__ eidx, float* __restrict__ hout, float* __restrict__ stats, int n) {
    __shared__ float sW[K * HD];
    __shared__ float sb[64], srb[64], ssw[64];
    __shared__ float ls[256], ls2[256];
    for (int i = threadIdx.x; i < K * HD; i += 256) sW[i] = rWp[i];
    if (threadIdx.x < 64) {
        sb[threadIdx.x] = b[threadIdx.x];
        srb[threadIdx.x] = rbp[threadIdx.x];
        ssw[threadIdx.x] = shiftW ? shiftW[threadIdx.x] : 0.f;
    }
    __syncthreads();
    const unsigned int* Xu = (const unsigned int*)xw;
    int wl = threadIdx.x >> 6, c = threadIdx.x & 63;
    int half = c >> 5;       // 0: even edge of pair, 1: odd edge
    int c2 = c & 31;         // dword column (covers cols 2*c2, 2*c2+1)
    float s = 0.f, s2 = 0.f;
    for (int row = blockIdx.x * 4 + wl; row < n; row += gridDim.x * 4) {
        const float* xr = x + (size_t)row * K;
        float res = srb[c];
#pragma unroll 8
        for (int k = 0; k < K; ++k) res = fmaf(xr[k], sW[k * HD + c], res);
        int beg = row_ptr[row], end = row_ptr[row + 1];
        float a0 = 0.f, a1 = 0.f;
        for (int e0 = beg; e0 < end; e0 += 64) {
            int m = end - e0;
            if (m > 64) m = 64;
            int my = (c < m) ? eidx[e0 + c] : 0;
            for (int j = 0; j < m; j += 8) {
                int i0 = j + half, i1 = i0 + 2, i2 = i0 + 4, i3 = i0 + 6;
                int s0 = __shfl(my, i0, 64);
                int s1 = __shfl(my, i1, 64);
                int s2i = __shfl(my, i2, 64);
                int s3 = __shfl(my, i3, 64);
                unsigned int p0 = (i0 < m) ? Xu[s0 * 32 + c2] : 0u;
                unsigned int p1 = (i1 < m) ? Xu[s1 * 32 + c2] : 0u;
                unsigned int p2 = (i2 < m) ? Xu[s2i * 32 + c2] : 0u;
                unsigned int p3 = (i3 < m) ? Xu[s3 * 32 + c2] : 0u;
                a0 += (bf_lo(p0) + bf_lo(p1)) + (bf_lo(p2) + bf_lo(p3));
                a1 += (bf_hi(p0) + bf_hi(p1)) + (bf_hi(p2) + bf_hi(p3));
            }
        }
        // combine even/odd halves, then redistribute pair-layout -> column-layout
        a0 += __shfl_xor(a0, 32, 64);
        a1 += __shfl_xor(a1, 32, 64);
        float t0 = __shfl(a0, c >> 1, 64);
        float t1 = __shfl(a1, c >> 1, 64);
        float agg = fmaf((float)(end - beg), ssw[c], sb[c]) + ((c & 1) ? t1 : t0);
        float hv = fmaxf(agg, 0.f) + fmaxf(res, 0.f);
        hout[(size_t)row * HD + c] = hv;
        s += hv;
        s2 += hv * hv;
    }
    ls[threadIdx.x] = s;
    ls2[threadIdx.x] = s2;
    __syncthreads();
    if (wl == 0) {
        float a = ls[c] + ls[64 + c] + ls[128 + c] + ls[192 + c];
        float a2 = ls2[c] + ls2[64 + c] + ls2[128 + c] + ls2[192 + c];
        atomicAdd(&stats[c], a);
        atomicAdd(&stats[64 + c], a2);
    }
}

// ---------------- readout ----------------

__global__ void readout_init_kernel(float* __restrict__ hsum, unsigned int* __restrict__ hmax,
                                    const float* __restrict__ stats, const float* __restrict__ g,
                                    const float* __restrict__ be, float* __restrict__ ss) {
    int idx = blockIdx.x * 256 + threadIdx.x;
    if (idx < NB * HD) {
        hsum[idx] = 0.f;
        hmax[idx] = 0x007FFFFFu;  // encoded(-inf)
    }
    if (blockIdx.x == 0 && threadIdx.x < 64) {
        int c = threadIdx.x;
        float mean = stats[c] / (float)NN;
        float var = stats[64 + c] / (float)NN - mean * mean;
        float scale = g[c] * rsqrtf(var + BN_EPS);
        ss[c] = scale;
        ss[64 + c] = be[c] - mean * scale;
    }
}

#define RNODES 16  // consecutive nodes per wave; gid sorted -> ~1 flush per wave

__device__ __forceinline__ void ro_flush(float* hsum, unsigned int* hmax, int g, int c,
                                         float accS, float accM) {
    atomicAdd(&hsum[g * HD + c], accS);
    unsigned int bits = __float_as_uint(accM);
    unsigned int enc = (bits & 0x80000000u) ? ~bits : (bits | 0x80000000u);
    atomicMax(&hmax[g * HD + c], enc);
}

__global__ __launch_bounds__(256) void readout_kernel(
    const float* __restrict__ h, const int* __restrict__ gid, const float* __restrict__ ss,
    const float* __restrict__ awW, const float* __restrict__ awb, float* __restrict__ hsum,
    unsigned int* __restrict__ hmax, int n) {
    int wid = blockIdx.x * 4 + (threadIdx.x >> 6);
    int c = threadIdx.x & 63;
    int r0 = wid * RNODES;
    if (r0 >= n) return;
    int r1 = r0 + RNODES;
    if (r1 > n) r1 = n;
    float aw = awW[c], ab = awb[0];
    float sA = ss[c], sB = ss[64 + c];
    int cur = gid[r0];
    float accS = 0.f, accM = -__builtin_inff();
    for (int r = r0; r < r1; ++r) {
        int g = gid[r];
        if (g != cur) {
            ro_flush(hsum, hmax, cur, c, accS, accM);
            accS = 0.f;
            accM = -__builtin_inff();
            cur = g;
        }
        float v = fmaf(h[(size_t)r * HD + c], sA, sB);
        float p = v * aw;
        for (int off = 32; off; off >>= 1) p += __shfl_xor(p, off, 64);
        float w = 1.f / (1.f + expf(-(p + ab)));
        accS = fmaf(v, w, accS);
        accM = fmaxf(accM, v);
    }
    ro_flush(hsum, hmax, cur, c, accS, accM);
}

__global__ void final_kernel(const float* __restrict__ hsum, const unsigned int* __restrict__ hmax,
                             const float* __restrict__ outW, const float* __restrict__ outb,
                             float* __restrict__ out) {
    __shared__ float sW[128 * 64];
    for (int i = threadIdx.x; i < 128 * 64; i += 256) sW[i] = outW[i];
    __syncthreads();
    int idx = blockIdx.x * 256 + threadIdx.x;
    if (idx >= NB * HD) return;
    int bi = idx >> 6, o = idx & 63;
    float acc = outb[o];
#pragma unroll 4
    for (int k = 0; k < 64; ++k) acc = fmaf(hsum[bi * 64 + k], sW[k * 64 + o], acc);
#pragma unroll 4
    for (int k = 0; k < 64; ++k) {
        unsigned int e = hmax[bi * 64 + k];
        float m;
        if (e == 0x007FFFFFu) {
            m = 0.f;  // empty graph
        } else {
            m = (e & 0x80000000u) ? __uint_as_float(e ^ 0x80000000u) : __uint_as_float(~e);
        }
        acc = fmaf(m, sW[(64 + k) * 64 + o], acc);
    }
    out[idx] = acc;
}

// ---------------- launch ----------------

extern "C" void kernel_launch(void* const* d_in, const int* in_sizes, int n_in,
                              void* d_out, int out_size, void* d_ws, size_t ws_size,
                              hipStream_t stream) {
    const float* feats = (const float*)d_in[0];
    const int* src = (const int*)d_in[1];
    const int* dst = (const int*)d_in[2];
    const int* gid = (const int*)d_in[3];
    const float* W[3];
    const float* b[3];
    const float* rW[3];
    const float* rb[3];
    const float* g[3];
    const float* be[3];
    for (int l = 0; l < 3; ++l) {
        W[l] = (const float*)d_in[4 + 6 * l + 0];
        b[l] = (const float*)d_in[4 + 6 * l + 1];
        rW[l] = (const float*)d_in[4 + 6 * l + 2];
        rb[l] = (const float*)d_in[4 + 6 * l + 3];
        g[l] = (const float*)d_in[4 + 6 * l + 4];
        be[l] = (const float*)d_in[4 + 6 * l + 5];
    }
    const float* awW = (const float*)d_in[22];
    const float* awb = (const float*)d_in[23];
    const float* outW = (const float*)d_in[24];
    const float* outb = (const float*)d_in[25];
    float* out = (float*)d_out;

    // workspace layout
    __hip_bfloat16* XW = (__hip_bfloat16*)d_ws;            // N*64 bf16
    float* P1 = (float*)(XW + (size_t)NN * HD);            // N*64 f32
    float* P2 = P1 + (size_t)NN * HD;                      // N*64 f32
    float* stats = P2 + (size_t)NN * HD;                   // 3*128
    float* ss2 = stats + 384;                              // 128
    float* Wp = ss2 + 128;                                 // 4096
    float* rWp = Wp + 4096;                                // 4096
    float* shW = rWp + 4096;                               // 64
    float* rbp = shW + 64;                                 // 64
    float* hsum = rbp + 64;                                // B*64
    unsigned int* hmax = (unsigned int*)(hsum + (size_t)NB * HD);  // B*64
    int* cnt = (int*)(hmax + (size_t)NB * HD);             // N
    int* cnt2 = cnt + NN;                                  // N
    int* row_ptr = cnt2 + NN;                              // N+1
    int* bsum = row_ptr + NN + 1;                          // NCHUNK
    int* eidx = bsum + NCHUNK;                             // E

    float* stats0 = stats;
    float* stats1 = stats + 128;
    float* stats2 = stats + 256;

    const int EBLK = (NE + 255) / 256;   // 3125
    const int GEMMBLK = 1280;
    const int FUSEBLK = 4096;
    const int ROBLK = (NN + RNODES * 4 - 1) / (RNODES * 4);  // 782

    // ---- CSR build ----
    csr_zero_kernel<<<(NN + 255) / 256, 256, 0, stream>>>(cnt, cnt2, stats);
    csr_hist_kernel<<<EBLK, 256, 0, stream>>>(dst, cnt);
    scanA_kernel<<<NCHUNK, SCHUNK, 0, stream>>>(cnt, bsum);
    scanB_kernel<<<1, 64, 0, stream>>>(bsum);
    scanC_kernel<<<NCHUNK, SCHUNK, 0, stream>>>(cnt, bsum, row_ptr);
    csr_fill_kernel<<<EBLK, 256, 0, stream>>>(src, dst, row_ptr, cnt2, eidx);

    // ---- layer 0 ----
    gemm_kernel<FIN><<<GEMMBLK, 256, 0, stream>>>(feats, W[0], XW, NN);
    fused_layer_kernel<FIN><<<FUSEBLK, 256, 0, stream>>>(feats, XW, rW[0], rb[0], b[0],
                                                         (const float*)nullptr, row_ptr, eidx,
                                                         P1, stats0, NN);

    // ---- layer 1 (fold BN0) ----
    fold_kernel<<<1, 256, 0, stream>>>(stats0, g[0], be[0], W[1], rW[1], rb[1], Wp, rWp, shW, rbp);
    gemm_kernel<HD><<<GEMMBLK, 256, 0, stream>>>(P1, Wp, XW, NN);
    fused_layer_kernel<HD><<<FUSEBLK, 256, 0, stream>>>(P1, XW, rWp, rbp, b[1], shW, row_ptr, eidx,
                                                        P2, stats1, NN);

    // ---- layer 2 (fold BN1) ----
    fold_kernel<<<1, 256, 0, stream>>>(stats1, g[1], be[1], W[2], rW[2], rb[2], Wp, rWp, shW, rbp);
    gemm_kernel<HD><<<GEMMBLK, 256, 0, stream>>>(P2, Wp, XW, NN);
    fused_layer_kernel<HD><<<FUSEBLK, 256, 0, stream>>>(P2, XW, rWp, rbp, b[2], shW, row_ptr, eidx,
                                                        P1, stats2, NN);

    // ---- readout (BN2 on the fly) ----
    readout_init_kernel<<<(NB * HD + 255) / 256, 256, 0, stream>>>(hsum, hmax, stats2, g[2], be[2], ss2);
    readout_kernel<<<ROBLK, 256, 0, stream>>>(P1, gid, ss2, awW, awb, hsum, hmax, NN);
    final_kernel<<<(NB * HD + 255) / 256, 256, 0, stream>>>(hsum, hmax, outW, outb, out);
}

// Round 5
// 485.919 us; speedup vs baseline: 2.1243x; 1.2646x over previous
//
#include <hip/hip_runtime.h>
#include <hip/hip_bf16.h>
#include <math.h>

#define NN 50000
#define NE 800000
#define NB 512
#define FIN 74
#define HD 64
#define BN_EPS 1e-5f

#define SCHUNK 512
#define NCHUNK ((NN + SCHUNK - 1) / SCHUNK)  // 98

#define CHUNK 32    // rows per block in fused kernel
#define WCAP 1024   // LDS edge-index capacity (avg window ~560, +20 sigma)
#define NBLK ((NN + CHUNK - 1) / CHUNK)  // 1563

// ---------------- CSR build (padded to multiple of 4 edges/row) ----------------

__global__ void csr_zero_kernel(int* __restrict__ cnt, int* __restrict__ cnt2,
                                float* __restrict__ stats012,
                                unsigned long long* __restrict__ xw_zrow) {
    int i = blockIdx.x * 256 + threadIdx.x;
    if (i < NN) { cnt[i] = 0; cnt2[i] = 0; }
    if (i < 384) stats012[i] = 0.f;
    if (i < 16) xw_zrow[i] = 0ull;  // XW row NN = 128 B of zeros
}

__global__ void csr_hist_kernel(const int* __restrict__ dst, int* __restrict__ cnt) {
    int e = blockIdx.x * 256 + threadIdx.x;
    if (e < NE) atomicAdd(&cnt[dst[e]], 1);
}

__device__ __forceinline__ int pad4(int d) { return (d + 3) & ~3; }

__global__ void scanA_kernel(const int* __restrict__ cnt, int* __restrict__ bsum) {
    __shared__ int l[SCHUNK];
    int i = blockIdx.x * SCHUNK + threadIdx.x;
    int v = (i < NN) ? pad4(cnt[i]) : 0;
    l[threadIdx.x] = v;
    __syncthreads();
    for (int off = SCHUNK / 2; off; off >>= 1) {
        if (threadIdx.x < off) l[threadIdx.x] += l[threadIdx.x + off];
        __syncthreads();
    }
    if (threadIdx.x == 0) bsum[blockIdx.x] = l[0];
}

// exclusive scan of 98 block sums with one wave (shfl-scan, no serial global chain)
__global__ void scanB_kernel(int* __restrict__ bsum) {
    int lane = threadIdx.x;  // 64 threads
    int v0 = (lane < NCHUNK) ? bsum[lane] : 0;
    int v1 = (64 + lane < NCHUNK) ? bsum[64 + lane] : 0;
    int s0 = v0, s1 = v1;
    for (int off = 1; off < 64; off <<= 1) {
        int t0 = __shfl_up(s0, off, 64);
        int t1 = __shfl_up(s1, off, 64);
        if (lane >= off) { s0 += t0; s1 += t1; }
    }
    int tot0 = __shfl(s0, 63, 64);
    if (lane < NCHUNK) bsum[lane] = s0 - v0;
    if (64 + lane < NCHUNK) bsum[64 + lane] = s1 - v1 + tot0;
}

__global__ void scanC_kernel(const int* __restrict__ cnt, const int* __restrict__ bsum,
                             int* __restrict__ row_ptr) {
    __shared__ int l[SCHUNK];
    int i = blockIdx.x * SCHUNK + threadIdx.x;
    int v = (i < NN) ? pad4(cnt[i]) : 0;
    l[threadIdx.x] = v;
    __syncthreads();
    for (int off = 1; off < SCHUNK; off <<= 1) {
        int t = (threadIdx.x >= off) ? l[threadIdx.x - off] : 0;
        __syncthreads();
        l[threadIdx.x] += t;
        __syncthreads();
    }
    int excl = l[threadIdx.x] - v + bsum[blockIdx.x];
    if (i < NN) row_ptr[i] = excl;
    if (i == NN - 1) row_ptr[NN] = excl + v;
}

// fill real edges + pad each row's tail with dummy index NN (zero row)
__global__ void csr_fill_kernel(const int* __restrict__ src, const int* __restrict__ dst,
                                const int* __restrict__ row_ptr, const int* __restrict__ cnt,
                                int* __restrict__ cnt2, int* __restrict__ eidx) {
    int i = blockIdx.x * 256 + threadIdx.x;
    if (i < NE) {
        int d = dst[i];
        int p = row_ptr[d] + atomicAdd(&cnt2[d], 1);
        eidx[p] = src[i];
    }
    if (i < NN) {
        int deg = cnt[i], st = row_ptr[i], pd = pad4(deg);
        for (int j = deg; j < pd; ++j) eidx[st + j] = NN;
    }
}

// ---------------- dense pieces ----------------

template <int K>
__global__ __launch_bounds__(256) void gemm_kernel(const float* __restrict__ x,
                                                   const float* __restrict__ W,
                                                   __hip_bfloat16* __restrict__ y, int n) {
    __shared__ float sW[K * HD];
    for (int i = threadIdx.x; i < K * HD; i += 256) sW[i] = W[i];
    __syncthreads();
    int wl = threadIdx.x >> 6, col = threadIdx.x & 63;
    for (int row = blockIdx.x * 4 + wl; row < n; row += gridDim.x * 4) {
        const float* xr = x + (size_t)row * K;
        float acc = 0.f;
#pragma unroll 8
        for (int k = 0; k < K; ++k) acc = fmaf(xr[k], sW[k * HD + col], acc);
        y[(size_t)row * HD + col] = __float2bfloat16(acc);
    }
}

__global__ void fold_kernel(const float* __restrict__ stats, const float* __restrict__ g,
                            const float* __restrict__ be, const float* __restrict__ W,
                            const float* __restrict__ rW, const float* __restrict__ rb,
                            float* __restrict__ Wp, float* __restrict__ rWp,
                            float* __restrict__ shiftW, float* __restrict__ rbp) {
    __shared__ float sc[64], sh[64];
    int t = threadIdx.x;
    if (t < 64) {
        float mean = stats[t] / (float)NN;
        float var = stats[64 + t] / (float)NN - mean * mean;
        float scale = g[t] * rsqrtf(var + BN_EPS);
        sc[t] = scale;
        sh[t] = be[t] - mean * scale;
    }
    __syncthreads();
    for (int i = t; i < 64 * 64; i += 256) {
        int k = i >> 6;
        Wp[i] = sc[k] * W[i];
        rWp[i] = sc[k] * rW[i];
    }
    if (t < 64) {
        float sw = 0.f, srw = 0.f;
        for (int k = 0; k < 64; ++k) {
            sw = fmaf(sh[k], W[k * 64 + t], sw);
            srw = fmaf(sh[k], rW[k * 64 + t], srw);
        }
        shiftW[t] = sw;
        rbp[t] = rb[t] + srw;
    }
}

__device__ __forceinline__ float bf_lo(unsigned int p) { return __uint_as_float(p << 16); }
__device__ __forceinline__ float bf_hi(unsigned int p) { return __uint_as_float(p & 0xffff0000u); }

// gather pipeline state: up to 4 8-B loads (= 16 edges) per row in flight
struct GState {
    unsigned long long p0, p1, p2, p3;
    int ng, bb, dg;
};

__device__ __forceinline__ int ld_idx(int pos, const int* __restrict__ sIdx,
                                      const int* __restrict__ geidx, int w0) {
    return (pos < WCAP) ? sIdx[pos] : geidx[w0 + pos];
}

__device__ __forceinline__ void g_issue(GState& S, int rr, int r0, int rlim,
                                        const int* __restrict__ sRP,
                                        const int* __restrict__ sDeg,
                                        const int* __restrict__ sIdx,
                                        const int* __restrict__ geidx, int w0,
                                        const unsigned long long* __restrict__ XWu,
                                        int q, int c16) {
    S.p0 = S.p1 = S.p2 = S.p3 = 0ull;
    S.ng = 0; S.bb = 0; S.dg = 0;
    if (rr < rlim) {
        int lo = sRP[rr - r0];
        int plen = sRP[rr - r0 + 1] - lo;
        S.bb = lo - w0;
        S.ng = plen >> 2;
        S.dg = sDeg[rr - r0];
        if (S.ng > 0) { int ix = ld_idx(S.bb + q, sIdx, geidx, w0);      S.p0 = XWu[(size_t)ix * 16 + c16]; }
        if (S.ng > 1) { int ix = ld_idx(S.bb + 4 + q, sIdx, geidx, w0);  S.p1 = XWu[(size_t)ix * 16 + c16]; }
        if (S.ng > 2) { int ix = ld_idx(S.bb + 8 + q, sIdx, geidx, w0);  S.p2 = XWu[(size_t)ix * 16 + c16]; }
        if (S.ng > 3) { int ix = ld_idx(S.bb + 12 + q, sIdx, geidx, w0); S.p3 = XWu[(size_t)ix * 16 + c16]; }
    }
}

template <int K>
__device__ __forceinline__ void g_consume(const GState& S, int rr, int r0, int rlim,
                                          const int* __restrict__ sIdx,
                                          const int* __restrict__ geidx, int w0,
                                          const unsigned long long* __restrict__ XWu,
                                          const float* __restrict__ sX,
                                          const float* __restrict__ sW,
                                          const float* __restrict__ sb,
                                          const float* __restrict__ srb,
                                          const float* __restrict__ ssw,
                                          float* __restrict__ hout,
                                          int q, int c16, int c,
                                          float& ssum, float& ssum2) {
    if (rr >= rlim) return;
    unsigned l0 = (unsigned)S.p0, h0 = (unsigned)(S.p0 >> 32);
    unsigned l1 = (unsigned)S.p1, h1 = (unsigned)(S.p1 >> 32);
    unsigned l2 = (unsigned)S.p2, h2 = (unsigned)(S.p2 >> 32);
    unsigned l3 = (unsigned)S.p3, h3 = (unsigned)(S.p3 >> 32);
    float a0 = (bf_lo(l0) + bf_lo(l1)) + (bf_lo(l2) + bf_lo(l3));
    float a1 = (bf_hi(l0) + bf_hi(l1)) + (bf_hi(l2) + bf_hi(l3));
    float a2 = (bf_lo(h0) + bf_lo(h1)) + (bf_lo(h2) + bf_lo(h3));
    float a3 = (bf_hi(h0) + bf_hi(h1)) + (bf_hi(h2) + bf_hi(h3));
    for (int k = 4; k < S.ng; ++k) {  // rare: degree > 16
        int ix = ld_idx(S.bb + 4 * k + q, sIdx, geidx, w0);
        unsigned long long u = XWu[(size_t)ix * 16 + c16];
        unsigned lo = (unsigned)u, hi = (unsigned)(u >> 32);
        a0 += bf_lo(lo); a1 += bf_hi(lo); a2 += bf_lo(hi); a3 += bf_hi(hi);
    }
    // reduce across the 4 edge-quads
    a0 += __shfl_xor(a0, 16, 64); a0 += __shfl_xor(a0, 32, 64);
    a1 += __shfl_xor(a1, 16, 64); a1 += __shfl_xor(a1, 32, 64);
    a2 += __shfl_xor(a2, 16, 64); a2 += __shfl_xor(a2, 32, 64);
    a3 += __shfl_xor(a3, 16, 64); a3 += __shfl_xor(a3, 32, 64);
    // redistribute: lane c takes col c = 4*(c>>2) + (c&3)
    float t0 = __shfl(a0, c >> 2, 64);
    float t1 = __shfl(a1, c >> 2, 64);
    float t2 = __shfl(a2, c >> 2, 64);
    float t3 = __shfl(a3, c >> 2, 64);
    float val = (c & 2) ? ((c & 1) ? t3 : t2) : ((c & 1) ? t1 : t0);
    // residual GEMM from LDS
    const float* xr = &sX[(rr - r0) * K];
    float res = srb[c];
#pragma unroll 8
    for (int k = 0; k < K; ++k) res = fmaf(xr[k], sW[k * HD + c], res);
    float agg = val + fmaf((float)S.dg, ssw[c], sb[c]);
    float hv = fmaxf(agg, 0.f) + fmaxf(res, 0.f);
    hout[(size_t)rr * HD + c] = hv;
    ssum += hv;
    ssum2 += hv * hv;
}

// fused: h = relu(gather + deg*shiftW + b) + relu(x @ rWp + rbp); stats += (h, h^2)
template <int K>
__global__ __launch_bounds__(256) void fused_layer_kernel(
    const float* __restrict__ x, const __hip_bfloat16* __restrict__ xw,
    const float* __restrict__ rWp, const float* __restrict__ rbp, const float* __restrict__ b,
    const float* __restrict__ shiftW, const int* __restrict__ row_ptr,
    const int* __restrict__ geidx, const int* __restrict__ degs,
    float* __restrict__ hout, float* __restrict__ stats, int n) {
    __shared__ float sW[K * HD];
    __shared__ float sX[CHUNK * K];
    __shared__ int sIdx[WCAP];
    __shared__ int sRP[CHUNK + 1];
    __shared__ int sDeg[CHUNK];
    __shared__ float sb[64], srb[64], ssw[64];
    __shared__ float ls[256], ls2[256];

    int r0 = blockIdx.x * CHUNK;
    int rlim = (r0 + CHUNK < n) ? r0 + CHUNK : n;
    int tid = threadIdx.x;

    if (tid <= CHUNK) {
        int rp = r0 + tid;
        sRP[tid] = row_ptr[(rp < NN) ? rp : NN];
    }
    __syncthreads();
    int w0 = sRP[0];
    int wlen = sRP[CHUNK] - w0;
    int wcap = (wlen < WCAP) ? wlen : WCAP;
    for (int i = tid; i < wcap; i += 256) sIdx[i] = geidx[w0 + i];
    int xcount = (rlim - r0) * K;
    for (int i = tid; i < xcount; i += 256) sX[i] = x[(size_t)r0 * K + i];
    for (int i = tid; i < K * HD; i += 256) sW[i] = rWp[i];
    if (tid < 64) {
        sb[tid] = b[tid];
        srb[tid] = rbp[tid];
        ssw[tid] = shiftW ? shiftW[tid] : 0.f;
    }
    if (tid < CHUNK) {
        int rp = r0 + tid;
        sDeg[tid] = (rp < n) ? degs[rp] : 0;
    }
    __syncthreads();

    const unsigned long long* XWu = (const unsigned long long*)xw;
    int wl = tid >> 6, c = tid & 63;
    int q = c >> 4;    // edge-quad 0..3
    int c16 = c & 15;  // 8-B chunk of the 128-B row
    float ssum = 0.f, ssum2 = 0.f;
    int rr0 = r0 + wl * 8;

    GState A, B;
    g_issue(A, rr0 + 0, r0, rlim, sRP, sDeg, sIdx, geidx, w0, XWu, q, c16);
    g_issue(B, rr0 + 1, r0, rlim, sRP, sDeg, sIdx, geidx, w0, XWu, q, c16);
    g_consume<K>(A, rr0 + 0, r0, rlim, sIdx, geidx, w0, XWu, sX, sW, sb, srb, ssw, hout, q, c16, c, ssum, ssum2);
    g_issue(A, rr0 + 2, r0, rlim, sRP, sDeg, sIdx, geidx, w0, XWu, q, c16);
    g_consume<K>(B, rr0 + 1, r0, rlim, sIdx, geidx, w0, XWu, sX, sW, sb, srb, ssw, hout, q, c16, c, ssum, ssum2);
    g_issue(B, rr0 + 3, r0, rlim, sRP, sDeg, sIdx, geidx, w0, XWu, q, c16);
    g_consume<K>(A, rr0 + 2, r0, rlim, sIdx, geidx, w0, XWu, sX, sW, sb, srb, ssw, hout, q, c16, c, ssum, ssum2);
    g_issue(A, rr0 + 4, r0, rlim, sRP, sDeg, sIdx, geidx, w0, XWu, q, c16);
    g_consume<K>(B, rr0 + 3, r0, rlim, sIdx, geidx, w0, XWu, sX, sW, sb, srb, ssw, hout, q, c16, c, ssum, ssum2);
    g_issue(B, rr0 + 5, r0, rlim, sRP, sDeg, sIdx, geidx, w0, XWu, q, c16);
    g_consume<K>(A, rr0 + 4, r0, rlim, sIdx, geidx, w0, XWu, sX, sW, sb, srb, ssw, hout, q, c16, c, ssum, ssum2);
    g_issue(A, rr0 + 6, r0, rlim, sRP, sDeg, sIdx, geidx, w0, XWu, q, c16);
    g_consume<K>(B, rr0 + 5, r0, rlim, sIdx, geidx, w0, XWu, sX, sW, sb, srb, ssw, hout, q, c16, c, ssum, ssum2);
    g_issue(B, rr0 + 7, r0, rlim, sRP, sDeg, sIdx, geidx, w0, XWu, q, c16);
    g_consume<K>(A, rr0 + 6, r0, rlim, sIdx, geidx, w0, XWu, sX, sW, sb, srb, ssw, hout, q, c16, c, ssum, ssum2);
    g_consume<K>(B, rr0 + 7, r0, rlim, sIdx, geidx, w0, XWu, sX, sW, sb, srb, ssw, hout, q, c16, c, ssum, ssum2);

    ls[tid] = ssum;
    ls2[tid] = ssum2;
    __syncthreads();
    if (wl == 0) {
        float a = ls[c] + ls[64 + c] + ls[128 + c] + ls[192 + c];
        float a2 = ls2[c] + ls2[64 + c] + ls2[128 + c] + ls2[192 + c];
        atomicAdd(&stats[c], a);
        atomicAdd(&stats[64 + c], a2);
    }
}

// ---------------- readout ----------------

__global__ void readout_init_kernel(float* __restrict__ hsum, unsigned int* __restrict__ hmax,
                                    const float* __restrict__ stats, const float* __restrict__ g,
                                    const float* __restrict__ be, float* __restrict__ ss) {
    int idx = blockIdx.x * 256 + threadIdx.x;
    if (idx < NB * HD) {
        hsum[idx] = 0.f;
        hmax[idx] = 0x007FFFFFu;  // encoded(-inf)
    }
    if (blockIdx.x == 0 && threadIdx.x < 64) {
        int c = threadIdx.x;
        float mean = stats[c] / (float)NN;
        float var = stats[64 + c] / (float)NN - mean * mean;
        float scale = g[c] * rsqrtf(var + BN_EPS);
        ss[c] = scale;
        ss[64 + c] = be[c] - mean * scale;
    }
}

#define RNODES 16

__device__ __forceinline__ void ro_flush(float* hsum, unsigned int* hmax, int g, int c,
                                         float accS, float accM) {
    atomicAdd(&hsum[g * HD + c], accS);
    unsigned int bits = __float_as_uint(accM);
    unsigned int enc = (bits & 0x80000000u) ? ~bits : (bits | 0x80000000u);
    atomicMax(&hmax[g * HD + c], enc);
}

__global__ __launch_bounds__(256) void readout_kernel(
    const float* __restrict__ h, const int* __restrict__ gid, const float* __restrict__ ss,
    const float* __restrict__ awW, const float* __restrict__ awb, float* __restrict__ hsum,
    unsigned int* __restrict__ hmax, int n) {
    int wid = blockIdx.x * 4 + (threadIdx.x >> 6);
    int c = threadIdx.x & 63;
    int r0 = wid * RNODES;
    if (r0 >= n) return;
    int r1 = r0 + RNODES;
    if (r1 > n) r1 = n;
    float aw = awW[c], ab = awb[0];
    float sA = ss[c], sB = ss[64 + c];
    int cur = gid[r0];
    float accS = 0.f, accM = -__builtin_inff();
    for (int r = r0; r < r1; ++r) {
        int g = gid[r];
        if (g != cur) {
            ro_flush(hsum, hmax, cur, c, accS, accM);
            accS = 0.f;
            accM = -__builtin_inff();
            cur = g;
        }
        float v = fmaf(h[(size_t)r * HD + c], sA, sB);
        float p = v * aw;
        for (int off = 32; off; off >>= 1) p += __shfl_xor(p, off, 64);
        float w = 1.f / (1.f + expf(-(p + ab)));
        accS = fmaf(v, w, accS);
        accM = fmaxf(accM, v);
    }
    ro_flush(hsum, hmax, cur, c, accS, accM);
}

__global__ void final_kernel(const float* __restrict__ hsum, const unsigned int* __restrict__ hmax,
                             const float* __restrict__ outW, const float* __restrict__ outb,
                             float* __restrict__ out) {
    __shared__ float sW[128 * 64];
    for (int i = threadIdx.x; i < 128 * 64; i += 256) sW[i] = outW[i];
    __syncthreads();
    int idx = blockIdx.x * 256 + threadIdx.x;
    if (idx >= NB * HD) return;
    int bi = idx >> 6, o = idx & 63;
    float acc = outb[o];
#pragma unroll 4
    for (int k = 0; k < 64; ++k) acc = fmaf(hsum[bi * 64 + k], sW[k * 64 + o], acc);
#pragma unroll 4
    for (int k = 0; k < 64; ++k) {
        unsigned int e = hmax[bi * 64 + k];
        float m;
        if (e == 0x007FFFFFu) {
            m = 0.f;  // empty graph
        } else {
            m = (e & 0x80000000u) ? __uint_as_float(e ^ 0x80000000u) : __uint_as_float(~e);
        }
        acc = fmaf(m, sW[(64 + k) * 64 + o], acc);
    }
    out[idx] = acc;
}

// ---------------- launch ----------------

extern "C" void kernel_launch(void* const* d_in, const int* in_sizes, int n_in,
                              void* d_out, int out_size, void* d_ws, size_t ws_size,
                              hipStream_t stream) {
    const float* feats = (const float*)d_in[0];
    const int* src = (const int*)d_in[1];
    const int* dst = (const int*)d_in[2];
    const int* gid = (const int*)d_in[3];
    const float* W[3];
    const float* b[3];
    const float* rW[3];
    const float* rb[3];
    const float* g[3];
    const float* be[3];
    for (int l = 0; l < 3; ++l) {
        W[l] = (const float*)d_in[4 + 6 * l + 0];
        b[l] = (const float*)d_in[4 + 6 * l + 1];
        rW[l] = (const float*)d_in[4 + 6 * l + 2];
        rb[l] = (const float*)d_in[4 + 6 * l + 3];
        g[l] = (const float*)d_in[4 + 6 * l + 4];
        be[l] = (const float*)d_in[4 + 6 * l + 5];
    }
    const float* awW = (const float*)d_in[22];
    const float* awb = (const float*)d_in[23];
    const float* outW = (const float*)d_in[24];
    const float* outb = (const float*)d_in[25];
    float* out = (float*)d_out;

    // workspace layout
    __hip_bfloat16* XW = (__hip_bfloat16*)d_ws;                 // (NN+1)*64 bf16 (row NN = zeros)
    float* P1 = (float*)(XW + (size_t)(NN + 1) * HD);           // N*64 f32
    float* P2 = P1 + (size_t)NN * HD;                           // N*64 f32
    float* stats = P2 + (size_t)NN * HD;                        // 3*128
    float* ss2 = stats + 384;                                   // 128
    float* Wp = ss2 + 128;                                      // 4096
    float* rWp = Wp + 4096;                                     // 4096
    float* shW = rWp + 4096;                                    // 64
    float* rbp = shW + 64;                                      // 64
    float* hsum = rbp + 64;                                     // B*64
    unsigned int* hmax = (unsigned int*)(hsum + (size_t)NB * HD);  // B*64
    int* cnt = (int*)(hmax + (size_t)NB * HD);                  // N (real degree)
    int* cnt2 = cnt + NN;                                       // N
    int* row_ptr = cnt2 + NN;                                   // N+1 (padded CSR)
    int* bsum = row_ptr + NN + 1;                               // NCHUNK
    int* eidx = bsum + NCHUNK;                                  // <= NE + 3*NN

    float* stats0 = stats;
    float* stats1 = stats + 128;
    float* stats2 = stats + 256;

    const int EBLK = (NE + 255) / 256;  // covers NE and NN
    const int GEMMBLK = 1280;
    const int ROBLK = (NN + RNODES * 4 - 1) / (RNODES * 4);

    // ---- CSR build (padded) ----
    csr_zero_kernel<<<(NN + 255) / 256, 256, 0, stream>>>(
        cnt, cnt2, stats, (unsigned long long*)(XW + (size_t)NN * HD));
    csr_hist_kernel<<<EBLK, 256, 0, stream>>>(dst, cnt);
    scanA_kernel<<<NCHUNK, SCHUNK, 0, stream>>>(cnt, bsum);
    scanB_kernel<<<1, 64, 0, stream>>>(bsum);
    scanC_kernel<<<NCHUNK, SCHUNK, 0, stream>>>(cnt, bsum, row_ptr);
    csr_fill_kernel<<<EBLK, 256, 0, stream>>>(src, dst, row_ptr, cnt, cnt2, eidx);

    // ---- layer 0 ----
    gemm_kernel<FIN><<<GEMMBLK, 256, 0, stream>>>(feats, W[0], XW, NN);
    fused_layer_kernel<FIN><<<NBLK, 256, 0, stream>>>(feats, XW, rW[0], rb[0], b[0],
                                                      (const float*)nullptr, row_ptr, eidx, cnt,
                                                      P1, stats0, NN);

    // ---- layer 1 (fold BN0) ----
    fold_kernel<<<1, 256, 0, stream>>>(stats0, g[0], be[0], W[1], rW[1], rb[1], Wp, rWp, shW, rbp);
    gemm_kernel<HD><<<GEMMBLK, 256, 0, stream>>>(P1, Wp, XW, NN);
    fused_layer_kernel<HD><<<NBLK, 256, 0, stream>>>(P1, XW, rWp, rbp, b[1], shW, row_ptr, eidx,
                                                     cnt, P2, stats1, NN);

    // ---- layer 2 (fold BN1) ----
    fold_kernel<<<1, 256, 0, stream>>>(stats1, g[1], be[1], W[2], rW[2], rb[2], Wp, rWp, shW, rbp);
    gemm_kernel<HD><<<GEMMBLK, 256, 0, stream>>>(P2, Wp, XW, NN);
    fused_layer_kernel<HD><<<NBLK, 256, 0, stream>>>(P2, XW, rWp, rbp, b[2], shW, row_ptr, eidx,
                                                     cnt, P1, stats2, NN);

    // ---- readout (BN2 on the fly) ----
    readout_init_kernel<<<(NB * HD + 255) / 256, 256, 0, stream>>>(hsum, hmax, stats2, g[2], be[2], ss2);
    readout_kernel<<<ROBLK, 256, 0, stream>>>(P1, gid, ss2, awW, awb, hsum, hmax, NN);
    final_kernel<<<(NB * HD + 255) / 256, 256, 0, stream>>>(hsum, hmax, outW, outb, out);
}